// Round 1
// baseline (884.835 us; speedup 1.0000x reference)
//
#include <hip/hip_runtime.h>

static constexpr int   NB      = 4;     // batches
static constexpr int   PP      = 1024;  // points per side
static constexpr int   DD      = 16;    // feature dim
static constexpr float EPSV    = 0.1f;
static constexpr float KE      = 14.42695041f;   // (1/eps) * log2(e)
static constexpr float KL      = 0.0693147181f;  // eps * ln(2)
static constexpr int   MAXIT   = 100;
static constexpr float THRESHV = 0.1f;

static constexpr int NBLK = 256;   // 64 blocks per batch group, all co-resident
static constexpr int NTHR = 512;   // 8 waves
static constexpr unsigned DONEG   = 1000000u;  // "group finished" slot value
static constexpr unsigned TAG1    = 1u;        // plain "value written" tag
static constexpr unsigned EXITBIT = 2u;        // g0 piggyback: last iteration

// ws layout (u32 idx) — 64B-stride slots (epilogue barrier + done/T only):
//   slot(block b)     : ws32[b*16]          [0..4095]
//   Tslot             : ws32[4096]
//   err_ws (floats)   : ws f-idx 4352 + n*128 + t   (pre-poisoned 0x7f = 3.4e38)
static constexpr int    ERR_F_OFF     = 4352;
static constexpr size_t WS_ZERO_BYTES = 4352 * 4;   // slots + Tslot + flags
static constexpr size_t ERR_BYTES     = 512 * 4;

// Tagged snapshot scratch lives at the start of each batch's out_C area.
// Each slot is 8B: (float payload, u32 tag), written exactly once per launch.
//   u slot (t,i): tsc[t*PP + i]          t in [0,100)
//   v slot (t,j): tsc[VOFF + t*PP + j]
static constexpr int    VOFF = MAXIT * PP;                     // 102400 (u64 idx)
static constexpr size_t TAGB = (size_t)2 * MAXIT * PP * 8;     // 1,638,400 B/batch

__device__ __forceinline__ float fexp2(float v) { return __builtin_amdgcn_exp2f(v); }
__device__ __forceinline__ float flog2(float v) { return __builtin_amdgcn_logf(v); }

__device__ __forceinline__ float aload(const float* p) {
    return __hip_atomic_load(p, __ATOMIC_RELAXED, __HIP_MEMORY_SCOPE_AGENT);
}
__device__ __forceinline__ void astore(float* p, float v) {
    __hip_atomic_store(p, v, __ATOMIC_RELAXED, __HIP_MEMORY_SCOPE_AGENT);
}
__device__ __forceinline__ unsigned aloadu(const unsigned* p) {
    return __hip_atomic_load(p, __ATOMIC_RELAXED, __HIP_MEMORY_SCOPE_AGENT);
}
__device__ __forceinline__ void astoreu(unsigned* p, unsigned v) {
    __hip_atomic_store(p, v, __ATOMIC_RELAXED, __HIP_MEMORY_SCOPE_AGENT);
}
__device__ __forceinline__ unsigned long long aload64(const unsigned long long* p) {
    return __hip_atomic_load(p, __ATOMIC_RELAXED, __HIP_MEMORY_SCOPE_AGENT);
}
__device__ __forceinline__ void astore_tag(unsigned long long* p, float v, unsigned tag) {
    union { unsigned long long u; unsigned w[2]; } c;
    c.w[0] = __float_as_uint(v); c.w[1] = tag;
    __hip_atomic_store(p, c.u, __ATOMIC_RELAXED, __HIP_MEMORY_SCOPE_AGENT);
}
// Poll two adjacent tagged slots until both tags are nonzero; payload arrives
// with the same 8B atomic load (single producer->consumer hop).
__device__ __forceinline__ void poll_pair(const unsigned long long* p,
                                          float& f0, float& f1, unsigned& tags) {
    unsigned long long a = aload64(p), b = aload64(p + 1);
    while (((unsigned)(a >> 32) == 0u) | ((unsigned)(b >> 32) == 0u)) {
        __builtin_amdgcn_s_sleep(1);
        a = aload64(p); b = aload64(p + 1);
    }
    f0 = __uint_as_float((unsigned)a);
    f1 = __uint_as_float((unsigned)b);
    tags = (unsigned)((a >> 32) | (b >> 32));
}

// slot barrier (epilogue only: all snapshot reads done before C overwrites tags)
__device__ __forceinline__ void gbar_group(unsigned* ws32, int n, int g, unsigned gen) {
    __syncthreads();
    if (threadIdx.x < 64) {
        if (threadIdx.x == 0) astoreu(ws32 + (n * 64 + g) * 16, gen);
        const unsigned* sp = ws32 + (n * 64 + threadIdx.x) * 16;
        while (__ballot(aloadu(sp) >= gen) != ~0ull)
            __builtin_amdgcn_s_sleep(1);
    }
    __syncthreads();
}

__global__ __launch_bounds__(NTHR, 2)
void sinkhorn_kernel(const float* __restrict__ x, const float* __restrict__ y,
                     const float* __restrict__ wx, const float* __restrict__ wy,
                     float* __restrict__ out, float* __restrict__ ws)
{
    __shared__ float rt[16 * PP];    // this block's 16 C-rows (64 KB)
    __shared__ float sbuf[PP];       // u/v broadcast buffer (4 KB)
    __shared__ float cred[8];        // per-wave partials (err, then cost)
    __shared__ int   Ts;             // chosen iteration T
    __shared__ int   s_last;         // "current iteration is the last"
    __shared__ int   s_exit_known;   // g0: convergence detected (set-once)

    unsigned* ws32  = (unsigned*)ws;
    unsigned* Tslot = ws32 + 4096;
    float*    ews   = ws + ERR_F_OFF;

    float* out_cost = out;
    float* out_pi   = out + NB;
    float* out_C    = out + NB + (size_t)NB * PP * PP;

    const int b   = blockIdx.x;
    const int n   = b >> 6;            // batch / group
    const int g   = b & 63;            // block within group
    const int i0  = g * 16;            // first row (and col) of this block
    const int w   = threadIdx.x >> 6;  // wave 0..7
    const int l   = threadIdx.x & 63;  // lane
    const int tid = threadIdx.x;

    // tagged snapshot scratch for this batch (inside its out_C area)
    unsigned long long* tsc = (unsigned long long*)(out_C + (size_t)n * PP * PP);

    if (tid == 0) { s_last = 0; s_exit_known = 0; }

    // ---------------- stage A: 16 C-rows -> LDS ----------------
    float4 xr[2][4];
    #pragma unroll
    for (int rr = 0; rr < 2; ++rr) {
        const float4* xp = (const float4*)(x + ((size_t)n * PP + (i0 + 2 * w + rr)) * DD);
        #pragma unroll
        for (int q = 0; q < 4; ++q) xr[rr][q] = xp[q];
    }
    #pragma unroll 4
    for (int k = 0; k < 16; ++k) {
        int j = l + 64 * k;
        const float4* yp = (const float4*)(y + ((size_t)n * PP + j) * DD);
        float4 y0 = yp[0], y1 = yp[1], y2 = yp[2], y3 = yp[3];
        #pragma unroll
        for (int rr = 0; rr < 2; ++rr) {
            float c = fabsf(xr[rr][0].x - y0.x) + fabsf(xr[rr][0].y - y0.y)
                    + fabsf(xr[rr][0].z - y0.z) + fabsf(xr[rr][0].w - y0.w)
                    + fabsf(xr[rr][1].x - y1.x) + fabsf(xr[rr][1].y - y1.y)
                    + fabsf(xr[rr][1].z - y1.z) + fabsf(xr[rr][1].w - y1.w)
                    + fabsf(xr[rr][2].x - y2.x) + fabsf(xr[rr][2].y - y2.y)
                    + fabsf(xr[rr][2].z - y2.z) + fabsf(xr[rr][2].w - y2.w)
                    + fabsf(xr[rr][3].x - y3.x) + fabsf(xr[rr][3].y - y3.y)
                    + fabsf(xr[rr][3].z - y3.z) + fabsf(xr[rr][3].w - y3.w);
            rt[(2 * w + rr) * PP + j] = c;
        }
    }

    // ---------------- stage B: 16 C-cols recomputed into registers ----------------
    float4 yc[2][4];
    #pragma unroll
    for (int c = 0; c < 2; ++c) {
        const float4* yp = (const float4*)(y + ((size_t)n * PP + (i0 + 2 * w + c)) * DD);
        #pragma unroll
        for (int q = 0; q < 4; ++q) yc[c][q] = yp[q];
    }
    float2 c2[16];
    #pragma unroll 4
    for (int k = 0; k < 16; ++k) {
        const float4* xp = (const float4*)(x + ((size_t)n * PP + (l + 64 * k)) * DD);
        float4 x0 = xp[0], x1 = xp[1], x2 = xp[2], x3 = xp[3];
        float cc[2];
        #pragma unroll
        for (int c = 0; c < 2; ++c) {
            cc[c] = fabsf(x0.x - yc[c][0].x) + fabsf(x0.y - yc[c][0].y)
                  + fabsf(x0.z - yc[c][0].z) + fabsf(x0.w - yc[c][0].w)
                  + fabsf(x1.x - yc[c][1].x) + fabsf(x1.y - yc[c][1].y)
                  + fabsf(x1.z - yc[c][1].z) + fabsf(x1.w - yc[c][1].w)
                  + fabsf(x2.x - yc[c][2].x) + fabsf(x2.y - yc[c][2].y)
                  + fabsf(x2.z - yc[c][2].z) + fabsf(x2.w - yc[c][2].w)
                  + fabsf(x3.x - yc[c][3].x) + fabsf(x3.y - yc[c][3].y)
                  + fabsf(x3.z - yc[c][3].z) + fabsf(x3.w - yc[c][3].w);
        }
        c2[k] = make_float2(cc[0], cc[1]);
    }

    float lmu[2], lnu[2];
    #pragma unroll
    for (int rr = 0; rr < 2; ++rr) {
        lmu[rr] = __logf(wx[n * PP + i0 + 2 * w + rr] + 1e-8f);
        lnu[rr] = __logf(wy[n * PP + i0 + 2 * w + rr] + 1e-8f);
    }

    // per-thread previous-u pair (indices 2*tid, 2*tid+1) for the err series
    float uprev0 = 0.f, uprev1 = 0.f;

    // ---------------- Sinkhorn loop (tagged data-flow sync) ----------------
    #pragma unroll 1
    for (int t = 0; t < MAXIT; ++t) {
        // ---- u-phase: gather v_{t-1} directly from tagged slots
        if (t == 0) {
            sbuf[2 * tid] = 0.f; sbuf[2 * tid + 1] = 0.f;
        } else {
            float v0, v1; unsigned tg;
            poll_pair(tsc + VOFF + (size_t)(t - 1) * PP + 2 * tid, v0, v1, tg);
            sbuf[2 * tid] = v0; sbuf[2 * tid + 1] = v1;
        }
        __syncthreads();

        {
            float4 tt[2][4];
            float m0 = -3.4e38f, m1 = -3.4e38f;
            #pragma unroll
            for (int k = 0; k < 4; ++k) {
                int j = 256 * k + 4 * l;
                float4 v4 = *(const float4*)&sbuf[j];
                float4 ca = *(const float4*)&rt[(2 * w) * PP + j];
                float4 cb = *(const float4*)&rt[(2 * w + 1) * PP + j];
                tt[0][k] = make_float4(v4.x - ca.x, v4.y - ca.y, v4.z - ca.z, v4.w - ca.w);
                tt[1][k] = make_float4(v4.x - cb.x, v4.y - cb.y, v4.z - cb.z, v4.w - cb.w);
                m0 = fmaxf(m0, fmaxf(fmaxf(tt[0][k].x, tt[0][k].y), fmaxf(tt[0][k].z, tt[0][k].w)));
                m1 = fmaxf(m1, fmaxf(fmaxf(tt[1][k].x, tt[1][k].y), fmaxf(tt[1][k].z, tt[1][k].w)));
            }
            #pragma unroll
            for (int off = 32; off >= 1; off >>= 1) {
                m0 = fmaxf(m0, __shfl_xor(m0, off));
                m1 = fmaxf(m1, __shfl_xor(m1, off));
            }
            float s0 = 0.f, s1 = 0.f;
            #pragma unroll
            for (int k = 0; k < 4; ++k) {
                s0 += fexp2((tt[0][k].x - m0) * KE) + fexp2((tt[0][k].y - m0) * KE)
                    + fexp2((tt[0][k].z - m0) * KE) + fexp2((tt[0][k].w - m0) * KE);
                s1 += fexp2((tt[1][k].x - m1) * KE) + fexp2((tt[1][k].y - m1) * KE)
                    + fexp2((tt[1][k].z - m1) * KE) + fexp2((tt[1][k].w - m1) * KE);
            }
            #pragma unroll
            for (int off = 32; off >= 1; off >>= 1) {
                s0 += __shfl_xor(s0, off);
                s1 += __shfl_xor(s1, off);
            }
            float un0 = EPSV * lmu[0] - (m0 + KL * flog2(s0));
            float un1 = EPSV * lmu[1] - (m1 + KL * flog2(s1));
            if (l == 0) {
                // g0 piggybacks the uniform exit decision on its u tags
                unsigned tg = TAG1 | ((g == 0 && s_exit_known) ? EXITBIT : 0u);
                astore_tag(tsc + (size_t)t * PP + i0 + 2 * w,     un0, tg);
                astore_tag(tsc + (size_t)t * PP + i0 + 2 * w + 1, un1, tg);
            }
        }
        __syncthreads();   // all sbuf(v) reads done before v-phase overwrites

        // ---- v-phase: gather full u_t from tagged slots; per-thread err
        {
            float ux, uy; unsigned tgs;
            poll_pair(tsc + (size_t)t * PP + 2 * tid, ux, uy, tgs);
            sbuf[2 * tid] = ux; sbuf[2 * tid + 1] = uy;
            if (tgs & EXITBIT) s_last = 1;   // only g0's slots (tid<8) carry it
            float we = fabsf(ux - uprev0) + fabsf(uy - uprev1);
            uprev0 = ux; uprev1 = uy;
            #pragma unroll
            for (int off = 32; off >= 1; off >>= 1) we += __shfl_xor(we, off);
            if (l == 0) cred[w] = we;
        }
        __syncthreads();

        // detection loads issued EARLY (hidden under v-LSE), ballots consumed late
        float d1 = 0.f, d2 = 0.f;
        const bool do_det = (g == 0) && (tid < 64) && (s_exit_known == 0);
        if (do_det) {
            d1 = aload(ews + 0 * 128 + tid) + aload(ews + 1 * 128 + tid)
               + aload(ews + 2 * 128 + tid) + aload(ews + 3 * 128 + tid);
            d2 = aload(ews + 0 * 128 + 64 + tid) + aload(ews + 1 * 128 + 64 + tid)
               + aload(ews + 2 * 128 + 64 + tid) + aload(ews + 3 * 128 + 64 + tid);
        }

        {
            float tt0[16], tt1[16], m0 = -3.4e38f, m1 = -3.4e38f;
            #pragma unroll
            for (int k = 0; k < 16; ++k) {
                float uu = sbuf[l + 64 * k];
                tt0[k] = uu - c2[k].x;
                tt1[k] = uu - c2[k].y;
                m0 = fmaxf(m0, tt0[k]);
                m1 = fmaxf(m1, tt1[k]);
            }
            #pragma unroll
            for (int off = 32; off >= 1; off >>= 1) {
                m0 = fmaxf(m0, __shfl_xor(m0, off));
                m1 = fmaxf(m1, __shfl_xor(m1, off));
            }
            float s0 = 0.f, s1 = 0.f;
            #pragma unroll
            for (int k = 0; k < 16; ++k) {
                s0 += fexp2((tt0[k] - m0) * KE);
                s1 += fexp2((tt1[k] - m1) * KE);
            }
            #pragma unroll
            for (int off = 32; off >= 1; off >>= 1) {
                s0 += __shfl_xor(s0, off);
                s1 += __shfl_xor(s1, off);
            }
            float vn0 = EPSV * lnu[0] - (m0 + KL * flog2(s0));
            float vn1 = EPSV * lnu[1] - (m1 + KL * flog2(s1));
            if (l == 0) {
                astore_tag(tsc + VOFF + (size_t)t * PP + i0 + 2 * w,     vn0, TAG1);
                astore_tag(tsc + VOFF + (size_t)t * PP + i0 + 2 * w + 1, vn1, TAG1);
            }
        }

        // deterministic batch err (fixed-order sum) for the final T-pick
        if (g == 0 && tid == 0) {
            float es = cred[0] + cred[1] + cred[2] + cred[3]
                     + cred[4] + cred[5] + cred[6] + cred[7];
            astore(ews + n * 128 + t, es);
        }
        if (do_det) {
            unsigned long long bb = __ballot(d1 < THRESHV * (float)NB)
                                  | __ballot(d2 < THRESHV * (float)NB);
            if (bb != 0ull && tid == 0) s_exit_known = 1;
        }

        __syncthreads();
        if (s_last) break;   // uniform across all blocks of all groups at same t
        // (reset below only happens when everyone read 0 -> benign rewrite)
        if (tid == 0) s_last = 0;
    }

    // ---------------- group-done signal, T-pick ----------------
    if (g == 0 && tid == 0)
        __hip_atomic_store(ws32 + (n * 64) * 16, DONEG,
                           __ATOMIC_RELEASE, __HIP_MEMORY_SCOPE_AGENT);

    if (b == 0 && tid < 64) {
        for (;;) {   // wait all 4 groups done (their err series final & visible)
            bool ok = (tid >= 4) ||
                (__hip_atomic_load(ws32 + tid * 64 * 16,
                                   __ATOMIC_ACQUIRE, __HIP_MEMORY_SCOPE_AGENT) >= DONEG);
            if (__ballot(ok) == ~0ull) break;
            __builtin_amdgcn_s_sleep(2);
        }
        float s1f = aload(ews + 0 * 128 + tid) + aload(ews + 1 * 128 + tid)
                  + aload(ews + 2 * 128 + tid) + aload(ews + 3 * 128 + tid);
        float s2f = aload(ews + 0 * 128 + 64 + tid) + aload(ews + 1 * 128 + 64 + tid)
                  + aload(ews + 2 * 128 + 64 + tid) + aload(ews + 3 * 128 + 64 + tid);
        unsigned long long b1 = __ballot(s1f < THRESHV * (float)NB);
        unsigned long long b2 = __ballot(s2f < THRESHV * (float)NB);
        int T = b1 ? (__ffsll((long long)b1) - 1)
                   : (b2 ? 64 + (__ffsll((long long)b2) - 1) : MAXIT - 1);
        if (tid == 0)
            __hip_atomic_store(Tslot, (unsigned)(T + 1),
                               __ATOMIC_RELEASE, __HIP_MEMORY_SCOPE_AGENT);
    }
    if (tid == 0) {
        unsigned tv;
        while ((tv = __hip_atomic_load(Tslot, __ATOMIC_ACQUIRE,
                                       __HIP_MEMORY_SCOPE_AGENT)) == 0u)
            __builtin_amdgcn_s_sleep(2);
        Ts = (int)tv - 1;
    }
    __syncthreads();
    const int T = Ts;

    // reload snapshot T via tag-polls (handles the MAXIT-cap case too)
    float u_loc[2];
    {
        unsigned tg;
        poll_pair(tsc + (size_t)T * PP + i0 + 2 * w, u_loc[0], u_loc[1], tg);
        float v0, v1;
        poll_pair(tsc + VOFF + (size_t)T * PP + 2 * tid, v0, v1, tg);
        sbuf[2 * tid] = v0; sbuf[2 * tid + 1] = v1;
    }
    // group's snapshot reads done before C overwrites the tag scratch
    gbar_group(ws32, n, g, DONEG + 1u);

    // ---------------- epilogue: write C, pi, cost ----------------
    float cacc = 0.f;
    #pragma unroll
    for (int rr = 0; rr < 2; ++rr) {
        int r = 2 * w + rr;
        int i = i0 + r;
        float un = u_loc[rr];
        #pragma unroll
        for (int k = 0; k < 4; ++k) {
            int j = 256 * k + 4 * l;
            float4 c4 = *(const float4*)&rt[r * PP + j];
            float4 v4 = *(const float4*)&sbuf[j];
            float4 p4;
            p4.x = fexp2((un + v4.x - c4.x) * KE);
            p4.y = fexp2((un + v4.y - c4.y) * KE);
            p4.z = fexp2((un + v4.z - c4.z) * KE);
            p4.w = fexp2((un + v4.w - c4.w) * KE);
            *(float4*)&out_pi[((size_t)n * PP + i) * PP + j] = p4;
            *(float4*)&out_C [((size_t)n * PP + i) * PP + j] = c4;
            cacc += p4.x * c4.x + p4.y * c4.y + p4.z * c4.z + p4.w * c4.w;
        }
    }
    #pragma unroll
    for (int off = 32; off >= 1; off >>= 1) cacc += __shfl_xor(cacc, off);
    if (l == 0) cred[w] = cacc;
    __syncthreads();
    if (tid == 0) {
        float s = 0.f;
        #pragma unroll
        for (int q = 0; q < 8; ++q) s += cred[q];
        atomicAdd(&out_cost[n], s);   // out_cost zeroed by memset
    }
}

extern "C" void kernel_launch(void* const* d_in, const int* in_sizes, int n_in,
                              void* d_out, int out_size, void* d_ws, size_t ws_size,
                              hipStream_t stream) {
    const float* x  = (const float*)d_in[0];
    const float* y  = (const float*)d_in[1];
    const float* wx = (const float*)d_in[2];
    const float* wy = (const float*)d_in[3];
    float* out = (float*)d_out;
    float* ws  = (float*)d_ws;

    (void)hipMemsetAsync(d_ws, 0, WS_ZERO_BYTES, stream);             // slots/Tslot
    (void)hipMemsetAsync((char*)d_ws + WS_ZERO_BYTES, 0x7f, ERR_BYTES, stream); // err = 3.4e38
    (void)hipMemsetAsync(d_out, 0, NB * sizeof(float), stream);       // cost accumulators
    // zero ALL per-batch tag regions (they live at the head of each batch's
    // out_C slab, 4MB apart; one span covers batch0..batch3's tag area —
    // everything in between is C scratch that gets fully rewritten anyway)
    {
        size_t out_C_off = ((size_t)NB + (size_t)NB * PP * PP) * sizeof(float);
        size_t span = (size_t)(NB - 1) * PP * PP * sizeof(float) + TAGB;
        (void)hipMemsetAsync((char*)d_out + out_C_off, 0, span, stream);
    }

    hipLaunchKernelGGL(sinkhorn_kernel, dim3(NBLK), dim3(NTHR), 0, stream,
                       x, y, wx, wy, out, ws);
}

// Round 2
// 873.843 us; speedup vs baseline: 1.0126x; 1.0126x over previous
//
#include <hip/hip_runtime.h>

static constexpr int   NB      = 4;     // batches
static constexpr int   PP      = 1024;  // points per side
static constexpr int   DD      = 16;    // feature dim
static constexpr float EPSV    = 0.1f;
static constexpr float KE      = 14.42695041f;   // (1/eps) * log2(e)
static constexpr float KL      = 0.0693147181f;  // eps * ln(2)
static constexpr int   MAXIT   = 100;
static constexpr float THRESHV = 0.1f;

static constexpr int NBLK = 512;   // 128 blocks per batch group; 2 blocks/CU
static constexpr int GPB  = 128;   // blocks per group
static constexpr int RPB  = 8;     // rows (and cols) per block
static constexpr int NTHR = 512;   // 8 waves; wave w owns row/col i0+w
static constexpr unsigned DONEG = 1000000u;   // "group finished" slot gen

// ws layout (u32 idx) — 64B-stride arrival slots (proven protocol, 512 slots):
//   slot(block b)     : ws32[b*16]          [0..8191]
//   Tslot             : ws32[8192]
//   exitf[n]          : ws32[8200+n]        (set-once, value = t_detect+1)
//   err_ws (floats)   : ws f-idx 8448 + n*128 + t   (pre-poisoned 0x7f = 3.4e38)
static constexpr int    ERR_F_OFF     = 8448;
static constexpr size_t WS_ZERO_BYTES = 8448 * 4;   // slots + Tslot + flags
static constexpr size_t ERR_BYTES     = 512 * 4;

// out_C scratch per batch (sc = out_C + n*PP*PP), valid until epilogue:
//   u_snap(t) = sc + t*PP ; v_snap(t) = sc + 131072 + t*PP
static constexpr int VSNAP_OFF = 131072;

__device__ __forceinline__ float fexp2(float v) { return __builtin_amdgcn_exp2f(v); }
__device__ __forceinline__ float flog2(float v) { return __builtin_amdgcn_logf(v); }

__device__ __forceinline__ float aload(const float* p) {
    return __hip_atomic_load(p, __ATOMIC_RELAXED, __HIP_MEMORY_SCOPE_AGENT);
}
__device__ __forceinline__ void astore(float* p, float v) {
    __hip_atomic_store(p, v, __ATOMIC_RELAXED, __HIP_MEMORY_SCOPE_AGENT);
}
__device__ __forceinline__ unsigned aloadu(const unsigned* p) {
    return __hip_atomic_load(p, __ATOMIC_RELAXED, __HIP_MEMORY_SCOPE_AGENT);
}
__device__ __forceinline__ void astoreu(unsigned* p, unsigned v) {
    __hip_atomic_store(p, v, __ATOMIC_RELAXED, __HIP_MEMORY_SCOPE_AGENT);
}
__device__ __forceinline__ float2 aload2(const float* p) {
    unsigned long long v = __hip_atomic_load((const unsigned long long*)p,
                                             __ATOMIC_RELAXED, __HIP_MEMORY_SCOPE_AGENT);
    union { unsigned long long u; float f[2]; } c; c.u = v;
    return make_float2(c.f[0], c.f[1]);
}

// Proven store+ballot-poll barrier, extended to 128 slots (2 per lane).
// Contract: all inter-block data is written with agent-scope relaxed atomics;
// __syncthreads drains vmcnt before s_barrier, so a block's data stores are at
// the coherence point before its arrival store.
__device__ __forceinline__ void gbar_group(unsigned* ws32, int n, int g, unsigned gen) {
    __syncthreads();
    if (threadIdx.x < 64) {
        if (threadIdx.x == 0) astoreu(ws32 + (n * GPB + g) * 16, gen);
        const unsigned* sa = ws32 + (n * GPB + 2 * threadIdx.x) * 16;
        const unsigned* sb = sa + 16;
        while (__ballot((aloadu(sa) >= gen) & (aloadu(sb) >= gen)) != ~0ull)
            __builtin_amdgcn_s_sleep(1);
    }
    __syncthreads();
}

__global__ __launch_bounds__(NTHR, 4)
void sinkhorn_kernel(const float* __restrict__ x, const float* __restrict__ y,
                     const float* __restrict__ wx, const float* __restrict__ wy,
                     float* __restrict__ out, float* __restrict__ ws)
{
    __shared__ float rt[RPB * PP];   // this block's 8 C-rows (32 KB)
    __shared__ float sbuf[PP];       // u/v broadcast buffer (4 KB)
    __shared__ float cred[8];        // per-wave partials (err, then cost)
    __shared__ int   Ts;             // chosen iteration T

    unsigned* ws32  = (unsigned*)ws;
    unsigned* Tslot = ws32 + 8192;
    unsigned* exitf = ws32 + 8200;
    float*    ews   = ws + ERR_F_OFF;

    float* out_cost = out;
    float* out_pi   = out + NB;
    float* out_C    = out + NB + (size_t)NB * PP * PP;

    const int b   = blockIdx.x;
    const int n   = b >> 7;            // batch / group
    const int g   = b & (GPB - 1);     // block within group
    const int i0  = g * RPB;           // first row (and col) of this block
    const int w   = threadIdx.x >> 6;  // wave 0..7  (owns row/col i0+w)
    const int l   = threadIdx.x & 63;  // lane
    const int tid = threadIdx.x;

    float* sc = out_C + (size_t)n * PP * PP;   // this batch's snapshot scratch

    // ---------------- stage A: 8 C-rows -> LDS (wave w does row i0+w) ----------------
    float4 xr[4];
    {
        const float4* xp = (const float4*)(x + ((size_t)n * PP + (i0 + w)) * DD);
        #pragma unroll
        for (int q = 0; q < 4; ++q) xr[q] = xp[q];
    }
    #pragma unroll 4
    for (int k = 0; k < 16; ++k) {
        int j = l + 64 * k;
        const float4* yp = (const float4*)(y + ((size_t)n * PP + j) * DD);
        float4 y0 = yp[0], y1 = yp[1], y2 = yp[2], y3 = yp[3];
        float c = fabsf(xr[0].x - y0.x) + fabsf(xr[0].y - y0.y)
                + fabsf(xr[0].z - y0.z) + fabsf(xr[0].w - y0.w)
                + fabsf(xr[1].x - y1.x) + fabsf(xr[1].y - y1.y)
                + fabsf(xr[1].z - y1.z) + fabsf(xr[1].w - y1.w)
                + fabsf(xr[2].x - y2.x) + fabsf(xr[2].y - y2.y)
                + fabsf(xr[2].z - y2.z) + fabsf(xr[2].w - y2.w)
                + fabsf(xr[3].x - y3.x) + fabsf(xr[3].y - y3.y)
                + fabsf(xr[3].z - y3.z) + fabsf(xr[3].w - y3.w);
        rt[w * PP + j] = c;
    }

    // ---------------- stage B: 8 C-cols recomputed into registers ----------------
    float4 yc[4];
    {
        const float4* yp = (const float4*)(y + ((size_t)n * PP + (i0 + w)) * DD);
        #pragma unroll
        for (int q = 0; q < 4; ++q) yc[q] = yp[q];
    }
    float c2[16];
    #pragma unroll 4
    for (int k = 0; k < 16; ++k) {
        const float4* xp = (const float4*)(x + ((size_t)n * PP + (l + 64 * k)) * DD);
        float4 x0 = xp[0], x1 = xp[1], x2 = xp[2], x3 = xp[3];
        c2[k] = fabsf(x0.x - yc[0].x) + fabsf(x0.y - yc[0].y)
              + fabsf(x0.z - yc[0].z) + fabsf(x0.w - yc[0].w)
              + fabsf(x1.x - yc[1].x) + fabsf(x1.y - yc[1].y)
              + fabsf(x1.z - yc[1].z) + fabsf(x1.w - yc[1].w)
              + fabsf(x2.x - yc[2].x) + fabsf(x2.y - yc[2].y)
              + fabsf(x2.z - yc[2].z) + fabsf(x2.w - yc[2].w)
              + fabsf(x3.x - yc[3].x) + fabsf(x3.y - yc[3].y)
              + fabsf(x3.z - yc[3].z) + fabsf(x3.w - yc[3].w);
    }

    const float lmu = __logf(wx[n * PP + i0 + w] + 1e-8f);
    const float lnu = __logf(wy[n * PP + i0 + w] + 1e-8f);

    // per-thread previous-u pair (indices 2*tid, 2*tid+1) for the err series
    float uprev0 = 0.f, uprev1 = 0.f;

    // ---------------- Sinkhorn loop (early-exit capable) ----------------
    #pragma unroll 1
    for (int t = 0; t < MAXIT; ++t) {
        // early-exit: flag set at t_set (v-phase) is drained before arrival(2*t_set+2);
        // every block crossed u-barrier(t_set+1) before reaching top t_set+2 -> uniform.
        if (t >= 2) {
            unsigned ef = aloadu(exitf + n);
            if (ef != 0u && t >= (int)ef + 1) break;
        }

        // ---- u-phase: u_{t+1}[i] = eps*log_mu[i] - eps*LSE_j((v_t[j] - C_ij)/eps)
        if (t == 0) {
            sbuf[2 * tid] = 0.f; sbuf[2 * tid + 1] = 0.f;
        } else {
            float2 vp = aload2(sc + VSNAP_OFF + (size_t)(t - 1) * PP + 2 * tid);
            sbuf[2 * tid] = vp.x; sbuf[2 * tid + 1] = vp.y;
        }
        __syncthreads();

        {
            float4 tt[4];
            float m0 = -3.4e38f;
            #pragma unroll
            for (int k = 0; k < 4; ++k) {
                int j = 256 * k + 4 * l;
                float4 v4 = *(const float4*)&sbuf[j];
                float4 ca = *(const float4*)&rt[w * PP + j];
                tt[k] = make_float4(v4.x - ca.x, v4.y - ca.y, v4.z - ca.z, v4.w - ca.w);
                m0 = fmaxf(m0, fmaxf(fmaxf(tt[k].x, tt[k].y), fmaxf(tt[k].z, tt[k].w)));
            }
            #pragma unroll
            for (int off = 32; off >= 1; off >>= 1)
                m0 = fmaxf(m0, __shfl_xor(m0, off));
            float s0 = 0.f;
            #pragma unroll
            for (int k = 0; k < 4; ++k) {
                s0 += fexp2((tt[k].x - m0) * KE) + fexp2((tt[k].y - m0) * KE)
                    + fexp2((tt[k].z - m0) * KE) + fexp2((tt[k].w - m0) * KE);
            }
            #pragma unroll
            for (int off = 32; off >= 1; off >>= 1)
                s0 += __shfl_xor(s0, off);
            float un0 = EPSV * lmu - (m0 + KL * flog2(s0));
            if (l == 0) astore(sc + (size_t)t * PP + i0 + w, un0);
        }

        gbar_group(ws32, n, g, (unsigned)(2 * t + 1));   // u_snap(t) visible

        // ---- v-phase: load full u_{t+1}; per-thread err vs previous u pair
        {
            float2 up = aload2(sc + (size_t)t * PP + 2 * tid);
            sbuf[2 * tid] = up.x; sbuf[2 * tid + 1] = up.y;
            float we = fabsf(up.x - uprev0) + fabsf(up.y - uprev1);
            uprev0 = up.x; uprev1 = up.y;
            #pragma unroll
            for (int off = 32; off >= 1; off >>= 1) we += __shfl_xor(we, off);
            if (l == 0) cred[w] = we;
        }
        __syncthreads();

        {
            float tt0[16], m0 = -3.4e38f;
            #pragma unroll
            for (int k = 0; k < 16; ++k) {
                float uu = sbuf[l + 64 * k];
                tt0[k] = uu - c2[k];
                m0 = fmaxf(m0, tt0[k]);
            }
            #pragma unroll
            for (int off = 32; off >= 1; off >>= 1)
                m0 = fmaxf(m0, __shfl_xor(m0, off));
            float s0 = 0.f;
            #pragma unroll
            for (int k = 0; k < 16; ++k)
                s0 += fexp2((tt0[k] - m0) * KE);
            #pragma unroll
            for (int off = 32; off >= 1; off >>= 1)
                s0 += __shfl_xor(s0, off);
            float vn0 = EPSV * lnu - (m0 + KL * flog2(s0));
            if (l == 0)
                astore(sc + VSNAP_OFF + (size_t)t * PP + i0 + w, vn0);
        }
        // deterministic batch err (fixed-order sum); stored before the barrier
        // -> drained before arrival(2t+2) -> visible whenever slot >= 2t+2.
        if (g == 0 && tid == 0) {
            float es = cred[0] + cred[1] + cred[2] + cred[3]
                     + cred[4] + cred[5] + cred[6] + cred[7];
            astore(ews + n * 128 + t, es);
        }

        // v-barrier + off-critical-path convergence detection (g==0 wave only)
        __syncthreads();
        if (tid < 64) {
            if (tid == 0) astoreu(ws32 + (n * GPB + g) * 16, (unsigned)(2 * t + 2));
            if (g == 0) {
                // lane l checks candidates t0=l and t0=64+l (unwritten slots = 3.4e38)
                float s1f = aload(ews + 0 * 128 + tid) + aload(ews + 1 * 128 + tid)
                          + aload(ews + 2 * 128 + tid) + aload(ews + 3 * 128 + tid);
                float s2f = aload(ews + 0 * 128 + 64 + tid) + aload(ews + 1 * 128 + 64 + tid)
                          + aload(ews + 2 * 128 + 64 + tid) + aload(ews + 3 * 128 + 64 + tid);
                unsigned long long bb = __ballot(s1f < THRESHV * (float)NB)
                                      | __ballot(s2f < THRESHV * (float)NB);
                if (bb != 0ull && tid == 0 && aloadu(exitf + n) == 0u)
                    astoreu(exitf + n, (unsigned)(t + 1));   // set-once
            }
            const unsigned* sa = ws32 + (n * GPB + 2 * tid) * 16;
            const unsigned* sb = sa + 16;
            while (__ballot((aloadu(sa) >= (unsigned)(2 * t + 2)) &
                            (aloadu(sb) >= (unsigned)(2 * t + 2))) != ~0ull)
                __builtin_amdgcn_s_sleep(1);
        }
        __syncthreads();
    }

    // ---------------- group-done signal, T-pick ----------------
    if (g == 0 && tid == 0) astoreu(ws32 + (n * GPB) * 16, DONEG);

    if (b == 0 && tid < 64) {
        for (;;) {   // wait all 4 groups done (their err series final & drained)
            bool ok = (tid >= 4) || (aloadu(ws32 + tid * GPB * 16) >= DONEG);
            if (__ballot(ok) == ~0ull) break;
            __builtin_amdgcn_s_sleep(2);
        }
        float s1f = aload(ews + 0 * 128 + tid) + aload(ews + 1 * 128 + tid)
                  + aload(ews + 2 * 128 + tid) + aload(ews + 3 * 128 + tid);
        float s2f = aload(ews + 0 * 128 + 64 + tid) + aload(ews + 1 * 128 + 64 + tid)
                  + aload(ews + 2 * 128 + 64 + tid) + aload(ews + 3 * 128 + 64 + tid);
        unsigned long long b1 = __ballot(s1f < THRESHV * (float)NB);
        unsigned long long b2 = __ballot(s2f < THRESHV * (float)NB);
        int T = b1 ? (__ffsll((long long)b1) - 1)
                   : (b2 ? 64 + (__ffsll((long long)b2) - 1) : MAXIT - 1);
        if (tid == 0) astoreu(Tslot, (unsigned)(T + 1));
    }
    if (tid == 0) {
        unsigned tv;
        while ((tv = aloadu(Tslot)) == 0u) __builtin_amdgcn_s_sleep(2);
        Ts = (int)tv - 1;
    }
    __syncthreads();
    const int T = Ts;

    // reload snapshot T: own u value (wave-uniform) + full v into sbuf
    float u_loc;
    {
        u_loc = aload(sc + (size_t)T * PP + i0 + w);
        float2 vp = aload2(sc + VSNAP_OFF + (size_t)T * PP + 2 * tid);
        sbuf[2 * tid] = vp.x; sbuf[2 * tid + 1] = vp.y;
    }
    // group's snapshot reads done before C overwrites the scratch region
    gbar_group(ws32, n, g, DONEG + 1u);

    // ---------------- epilogue: write C, pi, cost ----------------
    float cacc = 0.f;
    {
        int i = i0 + w;
        float un = u_loc;
        #pragma unroll
        for (int k = 0; k < 4; ++k) {
            int j = 256 * k + 4 * l;
            float4 c4 = *(const float4*)&rt[w * PP + j];
            float4 v4 = *(const float4*)&sbuf[j];
            float4 p4;
            p4.x = fexp2((un + v4.x - c4.x) * KE);
            p4.y = fexp2((un + v4.y - c4.y) * KE);
            p4.z = fexp2((un + v4.z - c4.z) * KE);
            p4.w = fexp2((un + v4.w - c4.w) * KE);
            *(float4*)&out_pi[((size_t)n * PP + i) * PP + j] = p4;
            *(float4*)&out_C [((size_t)n * PP + i) * PP + j] = c4;
            cacc += p4.x * c4.x + p4.y * c4.y + p4.z * c4.z + p4.w * c4.w;
        }
    }
    #pragma unroll
    for (int off = 32; off >= 1; off >>= 1) cacc += __shfl_xor(cacc, off);
    if (l == 0) cred[w] = cacc;
    __syncthreads();
    if (tid == 0) {
        float s = 0.f;
        #pragma unroll
        for (int q = 0; q < 8; ++q) s += cred[q];
        atomicAdd(&out_cost[n], s);   // out_cost zeroed by memset
    }
}

extern "C" void kernel_launch(void* const* d_in, const int* in_sizes, int n_in,
                              void* d_out, int out_size, void* d_ws, size_t ws_size,
                              hipStream_t stream) {
    const float* x  = (const float*)d_in[0];
    const float* y  = (const float*)d_in[1];
    const float* wx = (const float*)d_in[2];
    const float* wy = (const float*)d_in[3];
    float* out = (float*)d_out;
    float* ws  = (float*)d_ws;

    (void)hipMemsetAsync(d_ws, 0, WS_ZERO_BYTES, stream);             // slots/Tslot/flags
    (void)hipMemsetAsync((char*)d_ws + WS_ZERO_BYTES, 0x7f, ERR_BYTES, stream); // err = 3.4e38
    (void)hipMemsetAsync(d_out, 0, NB * sizeof(float), stream);       // cost accumulators

    hipLaunchKernelGGL(sinkhorn_kernel, dim3(NBLK), dim3(NTHR), 0, stream,
                       x, y, wx, wy, out, ws);
}

// Round 3
// 797.131 us; speedup vs baseline: 1.1100x; 1.0962x over previous
//
#include <hip/hip_runtime.h>

static constexpr int   NB      = 4;     // batches
static constexpr int   PP      = 1024;  // points per side
static constexpr int   DD      = 16;    // feature dim
static constexpr float EPSV    = 0.1f;
static constexpr float KE      = 14.42695041f;   // (1/eps) * log2(e)
static constexpr float KL      = 0.0693147181f;  // eps * ln(2)
static constexpr int   MAXIT   = 100;
static constexpr float THRESHV = 0.1f;

static constexpr int NBLK = 256;   // 64 blocks per batch group, all co-resident
static constexpr int NTHR = 512;   // 8 waves
static constexpr unsigned DONEG = 1000000u;   // "group finished" slot gen

// ws layout (u32 idx) — proven 64B-stride arrival slots:
//   slot(block b)     : ws32[b*16]          [0..4095]
//   Tslot             : ws32[4096]
//   exitf[n]          : ws32[4104+n]        (set-once, value = t_detect+1)
//   err_ws (floats)   : ws f-idx 4352 + n*128 + t   (pre-poisoned 0x7f = 3.4e38)
static constexpr int    ERR_F_OFF     = 4352;
static constexpr size_t WS_ZERO_BYTES = 4352 * 4;   // slots + Tslot + flags
static constexpr size_t ERR_BYTES     = 512 * 4;

// out_C scratch per batch (sc = out_C + n*PP*PP), valid until epilogue:
//   u_snap(t) = sc + t*PP ; v_snap(t) = sc + 131072 + t*PP   (write-once per t)
static constexpr int VSNAP_OFF = 131072;

__device__ __forceinline__ float fexp2(float v) { return __builtin_amdgcn_exp2f(v); }
__device__ __forceinline__ float flog2(float v) { return __builtin_amdgcn_logf(v); }

__device__ __forceinline__ float aload(const float* p) {
    return __hip_atomic_load(p, __ATOMIC_RELAXED, __HIP_MEMORY_SCOPE_AGENT);
}
__device__ __forceinline__ void astore(float* p, float v) {
    __hip_atomic_store(p, v, __ATOMIC_RELAXED, __HIP_MEMORY_SCOPE_AGENT);
}
__device__ __forceinline__ unsigned aloadu(const unsigned* p) {
    return __hip_atomic_load(p, __ATOMIC_RELAXED, __HIP_MEMORY_SCOPE_AGENT);
}
__device__ __forceinline__ void astoreu(unsigned* p, unsigned v) {
    __hip_atomic_store(p, v, __ATOMIC_RELAXED, __HIP_MEMORY_SCOPE_AGENT);
}
__device__ __forceinline__ float2 aload2(const float* p) {
    unsigned long long v = __hip_atomic_load((const unsigned long long*)p,
                                             __ATOMIC_RELAXED, __HIP_MEMORY_SCOPE_AGENT);
    union { unsigned long long u; float f[2]; } c; c.u = v;
    return make_float2(c.f[0], c.f[1]);
}
__device__ __forceinline__ void astore2(float* p, float a, float b) {
    union { unsigned long long u; float f[2]; } c; c.f[0] = a; c.f[1] = b;
    __hip_atomic_store((unsigned long long*)p, c.u,
                       __ATOMIC_RELAXED, __HIP_MEMORY_SCOPE_AGENT);
}

// padded LDS index: element e lives at (e/16)*17 + e%16  (bank-conflict-free)
__device__ __forceinline__ int pidx(int e) { return (e >> 4) * 17 + (e & 15); }

// Fused barrier-poll + snapshot-fetch (wave 0 only). Lane tid owns producer
// block 'tid' of this group: polls its slot for >= gen, and as soon as it
// appears, issues the 64B chunk loads (slot doubles as chunk-ready flag —
// addresses are write-once, so a seen slot implies final data). Loads overlap
// the residual poll of stragglers; LDS write after ballot-exit.
__device__ __forceinline__ void stage_poll(const unsigned* ws32, int n,
                                           const float* src, unsigned gen,
                                           float* sbuf2, int tid) {
    if (tid < 64) {
        const unsigned* sp = ws32 + (n * 64 + tid) * 16;
        const float* cp = src + tid * 16;
        float2 d0, d1, d2, d3, d4, d5, d6, d7;
        bool got = false;
        for (;;) {
            if (!got && aloadu(sp) >= gen) {
                d0 = aload2(cp + 0);  d1 = aload2(cp + 2);
                d2 = aload2(cp + 4);  d3 = aload2(cp + 6);
                d4 = aload2(cp + 8);  d5 = aload2(cp + 10);
                d6 = aload2(cp + 12); d7 = aload2(cp + 14);
                got = true;
            }
            if (__ballot(got) == ~0ull) break;
            __builtin_amdgcn_s_sleep(1);
        }
        float* dst = sbuf2 + tid * 17;   // lane-stride 17 floats: 2-way max (free)
        dst[0]  = d0.x; dst[1]  = d0.y; dst[2]  = d1.x; dst[3]  = d1.y;
        dst[4]  = d2.x; dst[5]  = d2.y; dst[6]  = d3.x; dst[7]  = d3.y;
        dst[8]  = d4.x; dst[9]  = d4.y; dst[10] = d5.x; dst[11] = d5.y;
        dst[12] = d6.x; dst[13] = d6.y; dst[14] = d7.x; dst[15] = d7.y;
    }
}

// plain slot barrier (epilogue only)
__device__ __forceinline__ void gbar_group(unsigned* ws32, int n, int g, unsigned gen) {
    __syncthreads();
    if (threadIdx.x < 64) {
        if (threadIdx.x == 0) astoreu(ws32 + (n * 64 + g) * 16, gen);
        const unsigned* sp = ws32 + (n * 64 + threadIdx.x) * 16;
        while (__ballot(aloadu(sp) >= gen) != ~0ull)
            __builtin_amdgcn_s_sleep(1);
    }
    __syncthreads();
}

__global__ __launch_bounds__(NTHR, 2)
void sinkhorn_kernel(const float* __restrict__ x, const float* __restrict__ y,
                     const float* __restrict__ wx, const float* __restrict__ wy,
                     float* __restrict__ out, float* __restrict__ ws)
{
    __shared__ float rt[16 * PP];    // this block's 16 C-rows (64 KB)
    __shared__ float sbuf2[1088];    // padded u/v broadcast buffer (4.25 KB)
    __shared__ float cred[8];        // per-wave partials (err, then cost)
    __shared__ int   Ts;             // chosen iteration T
    __shared__ int   s_ef;           // sampled exit flag (uniform break)

    unsigned* ws32  = (unsigned*)ws;
    unsigned* Tslot = ws32 + 4096;
    unsigned* exitf = ws32 + 4104;
    float*    ews   = ws + ERR_F_OFF;

    float* out_cost = out;
    float* out_pi   = out + NB;
    float* out_C    = out + NB + (size_t)NB * PP * PP;

    const int b   = blockIdx.x;
    const int n   = b >> 6;            // batch / group
    const int g   = b & 63;            // block within group
    const int i0  = g * 16;            // first row (and col) of this block
    const int w   = threadIdx.x >> 6;  // wave 0..7
    const int l   = threadIdx.x & 63;  // lane
    const int tid = threadIdx.x;

    float* sc = out_C + (size_t)n * PP * PP;   // this batch's snapshot scratch

    if (tid == 0) s_ef = 0;

    // ---------------- stage A: 16 C-rows -> LDS ----------------
    float4 xr[2][4];
    #pragma unroll
    for (int rr = 0; rr < 2; ++rr) {
        const float4* xp = (const float4*)(x + ((size_t)n * PP + (i0 + 2 * w + rr)) * DD);
        #pragma unroll
        for (int q = 0; q < 4; ++q) xr[rr][q] = xp[q];
    }
    #pragma unroll 4
    for (int k = 0; k < 16; ++k) {
        int j = l + 64 * k;
        const float4* yp = (const float4*)(y + ((size_t)n * PP + j) * DD);
        float4 y0 = yp[0], y1 = yp[1], y2 = yp[2], y3 = yp[3];
        #pragma unroll
        for (int rr = 0; rr < 2; ++rr) {
            float c = fabsf(xr[rr][0].x - y0.x) + fabsf(xr[rr][0].y - y0.y)
                    + fabsf(xr[rr][0].z - y0.z) + fabsf(xr[rr][0].w - y0.w)
                    + fabsf(xr[rr][1].x - y1.x) + fabsf(xr[rr][1].y - y1.y)
                    + fabsf(xr[rr][1].z - y1.z) + fabsf(xr[rr][1].w - y1.w)
                    + fabsf(xr[rr][2].x - y2.x) + fabsf(xr[rr][2].y - y2.y)
                    + fabsf(xr[rr][2].z - y2.z) + fabsf(xr[rr][2].w - y2.w)
                    + fabsf(xr[rr][3].x - y3.x) + fabsf(xr[rr][3].y - y3.y)
                    + fabsf(xr[rr][3].z - y3.z) + fabsf(xr[rr][3].w - y3.w);
            rt[(2 * w + rr) * PP + j] = c;
        }
    }

    // ---------------- stage B: 16 C-cols recomputed into registers ----------------
    float4 yc[2][4];
    #pragma unroll
    for (int c = 0; c < 2; ++c) {
        const float4* yp = (const float4*)(y + ((size_t)n * PP + (i0 + 2 * w + c)) * DD);
        #pragma unroll
        for (int q = 0; q < 4; ++q) yc[c][q] = yp[q];
    }
    float2 c2[16];
    #pragma unroll 4
    for (int k = 0; k < 16; ++k) {
        const float4* xp = (const float4*)(x + ((size_t)n * PP + (l + 64 * k)) * DD);
        float4 x0 = xp[0], x1 = xp[1], x2 = xp[2], x3 = xp[3];
        float cc[2];
        #pragma unroll
        for (int c = 0; c < 2; ++c) {
            cc[c] = fabsf(x0.x - yc[c][0].x) + fabsf(x0.y - yc[c][0].y)
                  + fabsf(x0.z - yc[c][0].z) + fabsf(x0.w - yc[c][0].w)
                  + fabsf(x1.x - yc[c][1].x) + fabsf(x1.y - yc[c][1].y)
                  + fabsf(x1.z - yc[c][1].z) + fabsf(x1.w - yc[c][1].w)
                  + fabsf(x2.x - yc[c][2].x) + fabsf(x2.y - yc[c][2].y)
                  + fabsf(x2.z - yc[c][2].z) + fabsf(x2.w - yc[c][2].w)
                  + fabsf(x3.x - yc[c][3].x) + fabsf(x3.y - yc[c][3].y)
                  + fabsf(x3.z - yc[c][3].z) + fabsf(x3.w - yc[c][3].w);
        }
        c2[k] = make_float2(cc[0], cc[1]);
    }

    float lmu[2], lnu[2];
    #pragma unroll
    for (int rr = 0; rr < 2; ++rr) {
        lmu[rr] = __logf(wx[n * PP + i0 + 2 * w + rr] + 1e-8f);
        lnu[rr] = __logf(wy[n * PP + i0 + 2 * w + rr] + 1e-8f);
    }

    // per-thread previous-u pair (indices 2*tid, 2*tid+1) for the err series
    float uprev0 = 0.f, uprev1 = 0.f;

    int last_t = 0;

    // ---------------- Sinkhorn loop (fused poll+fetch sync) ----------------
    #pragma unroll 1
    for (int t = 0; t < MAXIT; ++t) {
        // uniform early-exit: s_ef sampled (tid0 -> LDS) at end of prev iter
        if (t >= 2 && s_ef != 0 && t >= s_ef + 1) break;
        last_t = t;

        // ---- u-staging: fetch v_{t-1} (gated by each producer's 2t arrival)
        if (t == 0) {
            sbuf2[pidx(2 * tid)] = 0.f; sbuf2[pidx(2 * tid + 1)] = 0.f;
        } else {
            stage_poll(ws32, n, sc + VSNAP_OFF + (size_t)(t - 1) * PP,
                       (unsigned)(2 * t), sbuf2, tid);
        }
        __syncthreads();

        // ---- u-phase LSE
        {
            float4 tt[2][4];
            float m0 = -3.4e38f, m1 = -3.4e38f;
            #pragma unroll
            for (int k = 0; k < 4; ++k) {
                int j = 256 * k + 4 * l;
                float v0 = sbuf2[pidx(j)],     v1 = sbuf2[pidx(j + 1)];
                float v2 = sbuf2[pidx(j + 2)], v3 = sbuf2[pidx(j + 3)];
                float4 ca = *(const float4*)&rt[(2 * w) * PP + j];
                float4 cb = *(const float4*)&rt[(2 * w + 1) * PP + j];
                tt[0][k] = make_float4(v0 - ca.x, v1 - ca.y, v2 - ca.z, v3 - ca.w);
                tt[1][k] = make_float4(v0 - cb.x, v1 - cb.y, v2 - cb.z, v3 - cb.w);
                m0 = fmaxf(m0, fmaxf(fmaxf(tt[0][k].x, tt[0][k].y), fmaxf(tt[0][k].z, tt[0][k].w)));
                m1 = fmaxf(m1, fmaxf(fmaxf(tt[1][k].x, tt[1][k].y), fmaxf(tt[1][k].z, tt[1][k].w)));
            }
            #pragma unroll
            for (int off = 32; off >= 1; off >>= 1) {
                m0 = fmaxf(m0, __shfl_xor(m0, off));
                m1 = fmaxf(m1, __shfl_xor(m1, off));
            }
            float s0 = 0.f, s1 = 0.f;
            #pragma unroll
            for (int k = 0; k < 4; ++k) {
                s0 += fexp2((tt[0][k].x - m0) * KE) + fexp2((tt[0][k].y - m0) * KE)
                    + fexp2((tt[0][k].z - m0) * KE) + fexp2((tt[0][k].w - m0) * KE);
                s1 += fexp2((tt[1][k].x - m1) * KE) + fexp2((tt[1][k].y - m1) * KE)
                    + fexp2((tt[1][k].z - m1) * KE) + fexp2((tt[1][k].w - m1) * KE);
            }
            #pragma unroll
            for (int off = 32; off >= 1; off >>= 1) {
                s0 += __shfl_xor(s0, off);
                s1 += __shfl_xor(s1, off);
            }
            float un0 = EPSV * lmu[0] - (m0 + KL * flog2(s0));
            float un1 = EPSV * lmu[1] - (m1 + KL * flog2(s1));
            if (l == 0) astore2(sc + (size_t)t * PP + i0 + 2 * w, un0, un1);
        }
        __syncthreads();   // drain u stores (vmcnt) before arrival
        if (tid == 0) astoreu(ws32 + (n * 64 + g) * 16, (unsigned)(2 * t + 1));

        // ---- v-staging: fetch full u_t (gated by each producer's 2t+1 arrival)
        stage_poll(ws32, n, sc + (size_t)t * PP, (unsigned)(2 * t + 1), sbuf2, tid);
        __syncthreads();

        // ---- per-thread err vs previous u pair (same mapping as baseline)
        {
            float up0 = sbuf2[pidx(2 * tid)], up1 = sbuf2[pidx(2 * tid + 1)];
            float we = fabsf(up0 - uprev0) + fabsf(up1 - uprev1);
            uprev0 = up0; uprev1 = up1;
            #pragma unroll
            for (int off = 32; off >= 1; off >>= 1) we += __shfl_xor(we, off);
            if (l == 0) cred[w] = we;
        }
        __syncthreads();

        // ---- v-phase LSE
        {
            float tt0[16], tt1[16], m0 = -3.4e38f, m1 = -3.4e38f;
            #pragma unroll
            for (int k = 0; k < 16; ++k) {
                float uu = sbuf2[pidx(l + 64 * k)];
                tt0[k] = uu - c2[k].x;
                tt1[k] = uu - c2[k].y;
                m0 = fmaxf(m0, tt0[k]);
                m1 = fmaxf(m1, tt1[k]);
            }
            #pragma unroll
            for (int off = 32; off >= 1; off >>= 1) {
                m0 = fmaxf(m0, __shfl_xor(m0, off));
                m1 = fmaxf(m1, __shfl_xor(m1, off));
            }
            float s0 = 0.f, s1 = 0.f;
            #pragma unroll
            for (int k = 0; k < 16; ++k) {
                s0 += fexp2((tt0[k] - m0) * KE);
                s1 += fexp2((tt1[k] - m1) * KE);
            }
            #pragma unroll
            for (int off = 32; off >= 1; off >>= 1) {
                s0 += __shfl_xor(s0, off);
                s1 += __shfl_xor(s1, off);
            }
            float vn0 = EPSV * lnu[0] - (m0 + KL * flog2(s0));
            float vn1 = EPSV * lnu[1] - (m1 + KL * flog2(s1));
            if (l == 0)
                astore2(sc + VSNAP_OFF + (size_t)t * PP + i0 + 2 * w, vn0, vn1);
        }
        // deterministic batch err (fixed-order sum)
        if (g == 0 && tid == 0) {
            float es = cred[0] + cred[1] + cred[2] + cred[3]
                     + cred[4] + cred[5] + cred[6] + cred[7];
            astore(ews + n * 128 + t, es);
        }

        __syncthreads();   // drain v stores + errsum before arrival
        if (tid < 64) {
            if (tid == 0) astoreu(ws32 + (n * 64 + g) * 16, (unsigned)(2 * t + 2));
            if (g == 0) {
                // off-critical-path convergence detection (unwritten slots = 3.4e38)
                float s1f = aload(ews + 0 * 128 + tid) + aload(ews + 1 * 128 + tid)
                          + aload(ews + 2 * 128 + tid) + aload(ews + 3 * 128 + tid);
                float s2f = aload(ews + 0 * 128 + 64 + tid) + aload(ews + 1 * 128 + 64 + tid)
                          + aload(ews + 2 * 128 + 64 + tid) + aload(ews + 3 * 128 + 64 + tid);
                unsigned long long bb = __ballot(s1f < THRESHV * (float)NB)
                                      | __ballot(s2f < THRESHV * (float)NB);
                if (bb != 0ull && tid == 0 && aloadu(exitf + n) == 0u)
                    astoreu(exitf + n, (unsigned)(t + 1));   // set-once
            }
        }
        if (tid == 0) s_ef = (int)aloadu(exitf + n);   // sample for uniform break
        __syncthreads();
        // no end-of-iteration poll: fused into next iteration's u-staging
    }

    // ---------------- post-loop: final-iteration visibility ----------------
    // (replaces the removed last v-barrier; all mates executed the same last_t)
    {
        const unsigned need = (unsigned)(2 * last_t + 2);
        if (tid < 64) {
            const unsigned* sp = ws32 + (n * 64 + tid) * 16;
            while (__ballot(aloadu(sp) >= need) != ~0ull)
                __builtin_amdgcn_s_sleep(1);
        }
        __syncthreads();
    }

    // ---------------- group-done signal, T-pick ----------------
    if (g == 0 && tid == 0) astoreu(ws32 + (n * 64) * 16, DONEG);

    if (b == 0 && tid < 64) {
        for (;;) {   // wait all 4 groups done (their err series final & drained)
            bool ok = (tid >= 4) || (aloadu(ws32 + tid * 64 * 16) >= DONEG);
            if (__ballot(ok) == ~0ull) break;
            __builtin_amdgcn_s_sleep(2);
        }
        float s1f = aload(ews + 0 * 128 + tid) + aload(ews + 1 * 128 + tid)
                  + aload(ews + 2 * 128 + tid) + aload(ews + 3 * 128 + tid);
        float s2f = aload(ews + 0 * 128 + 64 + tid) + aload(ews + 1 * 128 + 64 + tid)
                  + aload(ews + 2 * 128 + 64 + tid) + aload(ews + 3 * 128 + 64 + tid);
        unsigned long long b1 = __ballot(s1f < THRESHV * (float)NB);
        unsigned long long b2 = __ballot(s2f < THRESHV * (float)NB);
        int T = b1 ? (__ffsll((long long)b1) - 1)
                   : (b2 ? 64 + (__ffsll((long long)b2) - 1) : MAXIT - 1);
        if (tid == 0) astoreu(Tslot, (unsigned)(T + 1));
    }
    if (tid == 0) {
        unsigned tv;
        while ((tv = aloadu(Tslot)) == 0u) __builtin_amdgcn_s_sleep(2);
        Ts = (int)tv - 1;
    }
    __syncthreads();
    const int T = Ts;

    // reload snapshot T: own u pair (broadcast) + full v into sbuf2
    float u_loc[2];
    {
        float2 up = aload2(sc + (size_t)T * PP + i0 + 2 * w);
        u_loc[0] = up.x; u_loc[1] = up.y;
        float2 vp = aload2(sc + VSNAP_OFF + (size_t)T * PP + 2 * tid);
        sbuf2[pidx(2 * tid)] = vp.x; sbuf2[pidx(2 * tid + 1)] = vp.y;
    }
    // group's snapshot reads done before C overwrites the scratch region
    gbar_group(ws32, n, g, DONEG + 1u);

    // ---------------- epilogue: write C, pi, cost ----------------
    float cacc = 0.f;
    #pragma unroll
    for (int rr = 0; rr < 2; ++rr) {
        int r = 2 * w + rr;
        int i = i0 + r;
        float un = u_loc[rr];
        #pragma unroll
        for (int k = 0; k < 4; ++k) {
            int j = 256 * k + 4 * l;
            float4 c4 = *(const float4*)&rt[r * PP + j];
            float v0 = sbuf2[pidx(j)],     v1 = sbuf2[pidx(j + 1)];
            float v2 = sbuf2[pidx(j + 2)], v3 = sbuf2[pidx(j + 3)];
            float4 p4;
            p4.x = fexp2((un + v0 - c4.x) * KE);
            p4.y = fexp2((un + v1 - c4.y) * KE);
            p4.z = fexp2((un + v2 - c4.z) * KE);
            p4.w = fexp2((un + v3 - c4.w) * KE);
            *(float4*)&out_pi[((size_t)n * PP + i) * PP + j] = p4;
            *(float4*)&out_C [((size_t)n * PP + i) * PP + j] = c4;
            cacc += p4.x * c4.x + p4.y * c4.y + p4.z * c4.z + p4.w * c4.w;
        }
    }
    #pragma unroll
    for (int off = 32; off >= 1; off >>= 1) cacc += __shfl_xor(cacc, off);
    if (l == 0) cred[w] = cacc;
    __syncthreads();
    if (tid == 0) {
        float s = 0.f;
        #pragma unroll
        for (int q = 0; q < 8; ++q) s += cred[q];
        atomicAdd(&out_cost[n], s);   // out_cost zeroed by memset
    }
}

extern "C" void kernel_launch(void* const* d_in, const int* in_sizes, int n_in,
                              void* d_out, int out_size, void* d_ws, size_t ws_size,
                              hipStream_t stream) {
    const float* x  = (const float*)d_in[0];
    const float* y  = (const float*)d_in[1];
    const float* wx = (const float*)d_in[2];
    const float* wy = (const float*)d_in[3];
    float* out = (float*)d_out;
    float* ws  = (float*)d_ws;

    (void)hipMemsetAsync(d_ws, 0, WS_ZERO_BYTES, stream);             // slots/Tslot/flags
    (void)hipMemsetAsync((char*)d_ws + WS_ZERO_BYTES, 0x7f, ERR_BYTES, stream); // err = 3.4e38
    (void)hipMemsetAsync(d_out, 0, NB * sizeof(float), stream);       // cost accumulators

    hipLaunchKernelGGL(sinkhorn_kernel, dim3(NBLK), dim3(NTHR), 0, stream,
                       x, y, wx, wy, out, ws);
}